// Round 9
// baseline (7841.766 us; speedup 1.0000x reference)
//
#include <hip/hip_runtime.h>
#include <hip/hip_bf16.h>
#include <math.h>

// ---------------- problem constants ----------------
#define N_ALL 1280     // B*S
#define NCHUNK 8
#define CH (N_ALL / NCHUNK)   // 160 samples per chunk
#define L0 2048
#define L1 1021
#define L2 509
#define L3 254
#define C1 64
#define C2 128
#define C3 256
#define C4 128         // a1/a2 out channels
#define DD 128         // proto dim
#define NP 200         // prototypes
#define PPAD 256
#define H1S 1024       // padded strides
#define H2S 512
#define H3S 256
// weight-staging row pitch: ODD so that successive rows shift banks by
// 4*133 mod 32 = 20 -> staging writes are ~2-way (free) instead of 6-8-way.
#define WPITCH 133

// ---------------- workspace layout (floats), macro-derived ----------------
#define H1_FLOATS ((size_t)CH * C1 * H1S)     // 10,485,760 ; h3 aliases (CH*C3*H3S equal)
#define H2_FLOATS ((size_t)CH * C2 * H2S)     // 10,485,760 ; holds h4 (first half) + h (second half)
#define PMIN_FLOATS ((size_t)N_ALL * 4 * PPAD)
#define ACTS_FLOATS ((size_t)N_ALL * NP)
#define WS_H1   ((size_t)0)
#define WS_H2   (WS_H1 + H1_FLOATS)
#define WS_PMIN (WS_H2 + H2_FLOATS)
#define WS_P2   (WS_PMIN + PMIN_FLOATS)
#define WS_ACTS (WS_P2 + PPAD)
#define WS_X2   (WS_ACTS + ACTS_FLOATS)
// total = 22,579,456 floats ~= 90.3 MB

// ======================================================================
// p2[p] = sum_d protos[p][d]^2  (256 entries, 0 for pad)
__global__ __launch_bounds__(256) void k_p2(const float* __restrict__ protos,
                                            float* __restrict__ p2) {
  int p = threadIdx.x;
  if (p < NP) {
    float s = 0.f;
    for (int d = 0; d < DD; ++d) { float v = protos[p * DD + d]; s = fmaf(v, v, s); }
    p2[p] = s;
  } else {
    p2[p] = 0.f;
  }
}

// ======================================================================
// conv1: x(n,2048) -> h1(n_local, 64, 1021 pad 1024), k=7 s=2, relu
__global__ __launch_bounds__(256) void k_conv1(const float* __restrict__ x,
                                               const float* __restrict__ w1,
                                               const float* __restrict__ b1,
                                               float* __restrict__ h1, int n0) {
  __shared__ float xs[L0];
  __shared__ float w1s[C1 * 7];
  __shared__ float b1s[C1];
  int tid = threadIdx.x;
  int chalf = blockIdx.x;
  int n = n0 + blockIdx.y;
  const float* xr = x + (size_t)n * L0;
  for (int i = tid; i < L0 / 4; i += 256)
    ((float4*)xs)[i] = ((const float4*)xr)[i];
  for (int i = tid; i < C1 * 7; i += 256) w1s[i] = w1[i];
  if (tid < C1) b1s[tid] = b1[tid];
  __syncthreads();
  float* hr = h1 + (size_t)blockIdx.y * C1 * H1S;
  for (int cl = 0; cl < 32; ++cl) {
    int c = chalf * 32 + cl;
    float wv0 = w1s[c * 7 + 0], wv1 = w1s[c * 7 + 1], wv2 = w1s[c * 7 + 2],
          wv3 = w1s[c * 7 + 3], wv4 = w1s[c * 7 + 4], wv5 = w1s[c * 7 + 5],
          wv6 = w1s[c * 7 + 6];
    float bb = b1s[c];
    for (int l = tid; l < L1; l += 256) {
      const float* xx = xs + 2 * l;
      float s = bb;
      s = fmaf(wv0, xx[0], s); s = fmaf(wv1, xx[1], s); s = fmaf(wv2, xx[2], s);
      s = fmaf(wv3, xx[3], s); s = fmaf(wv4, xx[4], s); s = fmaf(wv5, xx[5], s);
      s = fmaf(wv6, xx[6], s);
      hr[c * H1S + l] = fmaxf(s, 0.f);
    }
  }
}

// ======================================================================
// conv2: h1(n,64,1024) -> h2(n,128,509 pad 512), k=5 s=2, relu
// LDS: hs chunk 16ci (8.7KB) + wsc (42.6KB) = 51.3KB -> 3 blocks/CU
__global__ __launch_bounds__(256) void k_conv2(const float* __restrict__ h1,
                                               const float* __restrict__ w2,
                                               const float* __restrict__ b2,
                                               float* __restrict__ h2) {
  __shared__ float hs[16 * 136];          // input window chunk [cil][136]
  __shared__ float wsc[80 * WPITCH];      // [cil*5+k][co pad WPITCH]
  int tile = blockIdx.x;
  int n = blockIdx.y;
  int l0 = tile * 64;
  int c0 = 2 * l0;
  int tid = threadIdx.x;
  int tx = tid & 15, ty = tid >> 4;

  const float* h1b = h1 + (size_t)n * C1 * H1S + c0;

  float acc[8][4];
#pragma unroll
  for (int i = 0; i < 8; ++i)
#pragma unroll
    for (int j = 0; j < 4; ++j) acc[i][j] = 0.f;

  for (int ci0 = 0; ci0 < C1; ci0 += 16) {
    __syncthreads();
    // stage input chunk rows ci0..ci0+15, cols c0..c0+131
    for (int idx = tid; idx < 16 * 33; idx += 256) {
      int cil = idx / 33, m4 = idx - cil * 33;
      float4 v = *(const float4*)(h1b + (size_t)(ci0 + cil) * H1S + 4 * m4);
      *(float4*)&hs[cil * 136 + 4 * m4] = v;
    }
    // stage w2 chunk: 128 co x (16 ci x 5 k) -> transposed [r][co]
    for (int idx = tid; idx < C2 * 20; idx += 256) {
      int co = idx / 20, q = idx - co * 20;
      float4 v = *(const float4*)(w2 + (size_t)co * (C1 * 5) + ci0 * 5 + 4 * q);
      int r = 4 * q;
      wsc[(r + 0) * WPITCH + co] = v.x;
      wsc[(r + 1) * WPITCH + co] = v.y;
      wsc[(r + 2) * WPITCH + co] = v.z;
      wsc[(r + 3) * WPITCH + co] = v.w;
    }
    __syncthreads();
#pragma unroll 2
    for (int cil = 0; cil < 16; ++cil) {
#pragma unroll
      for (int k = 0; k < 5; ++k) {
        const float* wrow = wsc + (cil * 5 + k) * WPITCH + ty * 8;
        float4 a0 = *(const float4*)wrow;
        float4 a1 = *(const float4*)(wrow + 4);
        float av[8] = {a0.x, a0.y, a0.z, a0.w, a1.x, a1.y, a1.z, a1.w};
        float xv[4];
#pragma unroll
        for (int j = 0; j < 4; ++j) xv[j] = hs[cil * 136 + 2 * (tx + 16 * j) + k];
#pragma unroll
        for (int i = 0; i < 8; ++i)
#pragma unroll
          for (int j = 0; j < 4; ++j) acc[i][j] = fmaf(av[i], xv[j], acc[i][j]);
      }
    }
  }
  // epilogue
  float bb[8];
#pragma unroll
  for (int i = 0; i < 8; ++i) bb[i] = b2[ty * 8 + i];
  float* h2b = h2 + (size_t)n * C2 * H2S + l0;
#pragma unroll
  for (int i = 0; i < 8; ++i) {
    int co = ty * 8 + i;
#pragma unroll
    for (int j = 0; j < 4; ++j) {
      int lc = tx + 16 * j;
      h2b[(size_t)co * H2S + lc] = fmaxf(acc[i][j] + bb[i], 0.f);
    }
  }
}

// ======================================================================
// conv3: h2(n,128,512) -> h3(n,256,254 pad 256), k=3 s=2, relu
__global__ __launch_bounds__(256) void k_conv3(const float* __restrict__ h2,
                                               const float* __restrict__ w3,
                                               const float* __restrict__ b3,
                                               float* __restrict__ h3) {
  __shared__ float hs2[16 * 136];         // chunk window [cil][136]
  __shared__ float ws3[48 * WPITCH];      // [cil*3+k][co pad WPITCH]
  int tile = blockIdx.x;
  int co0 = blockIdx.y * 128;
  int n = blockIdx.z;
  int l0 = tile * 64;
  int tid = threadIdx.x;
  int tx = tid & 15, ty = tid >> 4;

  const float* h2b = h2 + (size_t)n * C2 * H2S + 2 * l0;

  float acc[8][4];
#pragma unroll
  for (int i = 0; i < 8; ++i)
#pragma unroll
    for (int j = 0; j < 4; ++j) acc[i][j] = 0.f;

  for (int ci0 = 0; ci0 < C2; ci0 += 16) {
    __syncthreads();
    for (int idx = tid; idx < 16 * 33; idx += 256) {
      int cil = idx / 33, m4 = idx - cil * 33;
      float4 v = *(const float4*)(h2b + (size_t)(ci0 + cil) * H2S + 4 * m4);
      *(float4*)&hs2[cil * 136 + 4 * m4] = v;
    }
    for (int idx = tid; idx < 128 * 12; idx += 256) {
      int co = idx / 12, q = idx - co * 12;
      float4 v = *(const float4*)(w3 + (size_t)(co0 + co) * (C2 * 3) + ci0 * 3 + 4 * q);
      int r = 4 * q;
      ws3[(r + 0) * WPITCH + co] = v.x;
      ws3[(r + 1) * WPITCH + co] = v.y;
      ws3[(r + 2) * WPITCH + co] = v.z;
      ws3[(r + 3) * WPITCH + co] = v.w;
    }
    __syncthreads();
#pragma unroll 2
    for (int cil = 0; cil < 16; ++cil) {
#pragma unroll
      for (int k = 0; k < 3; ++k) {
        const float* wrow = ws3 + (cil * 3 + k) * WPITCH + ty * 8;
        float4 a0 = *(const float4*)wrow;
        float4 a1 = *(const float4*)(wrow + 4);
        float av[8] = {a0.x, a0.y, a0.z, a0.w, a1.x, a1.y, a1.z, a1.w};
        float xv[4];
#pragma unroll
        for (int j = 0; j < 4; ++j) xv[j] = hs2[cil * 136 + 2 * (tx + 16 * j) + k];
#pragma unroll
        for (int i = 0; i < 8; ++i)
#pragma unroll
          for (int j = 0; j < 4; ++j) acc[i][j] = fmaf(av[i], xv[j], acc[i][j]);
      }
    }
  }
  float bb[8];
#pragma unroll
  for (int i = 0; i < 8; ++i) bb[i] = b3[co0 + ty * 8 + i];
  float* h3b = h3 + (size_t)n * C3 * H3S + l0;
#pragma unroll
  for (int i = 0; i < 8; ++i) {
    int co = co0 + ty * 8 + i;
#pragma unroll
    for (int j = 0; j < 4; ++j) {
      int lc = tx + 16 * j;
      h3b[(size_t)co * H3S + lc] = fmaxf(acc[i][j] + bb[i], 0.f);
    }
  }
}

// ======================================================================
// gemm1: h4 = relu(a1 @ h3 + ab1). Per (tile,n): 128co x 64l, K=256.
// LDS 25KB. Thread tile 8co x 4 consecutive l (l = tx*4+j).
__global__ __launch_bounds__(256) void k_gemm1(const float* __restrict__ h3g,
                                               const float* __restrict__ a1,
                                               const float* __restrict__ ab1,
                                               float* __restrict__ h4g) {
  __shared__ float hs[32 * 64];           // 8KB
  __shared__ float wa[32 * WPITCH];       // 17KB
  int tile = blockIdx.x, n = blockIdx.y;
  int l0 = tile * 64;
  int tid = threadIdx.x, tx = tid & 15, ty = tid >> 4;
  const float* h3b = h3g + (size_t)n * C3 * H3S + l0;

  float acc[8][4];
#pragma unroll
  for (int i = 0; i < 8; ++i)
#pragma unroll
    for (int j = 0; j < 4; ++j) acc[i][j] = 0.f;

  for (int ci0 = 0; ci0 < C3; ci0 += 32) {
    __syncthreads();
    for (int idx = tid; idx < 512; idx += 256) {
      int cil = idx >> 4, q = idx & 15;
      *(float4*)&hs[cil * 64 + 4 * q] =
          *(const float4*)(h3b + (size_t)(ci0 + cil) * H3S + 4 * q);
    }
    for (int idx = tid; idx < 1024; idx += 256) {
      int co = idx >> 3, q = idx & 7;
      float4 v = *(const float4*)(a1 + (size_t)co * C3 + ci0 + 4 * q);
      int r = 4 * q;
      wa[(r + 0) * WPITCH + co] = v.x;
      wa[(r + 1) * WPITCH + co] = v.y;
      wa[(r + 2) * WPITCH + co] = v.z;
      wa[(r + 3) * WPITCH + co] = v.w;
    }
    __syncthreads();
#pragma unroll 8
    for (int cil = 0; cil < 32; ++cil) {
      const float* wrow = wa + cil * WPITCH + ty * 8;
      float4 a0 = *(const float4*)wrow;
      float4 a1v = *(const float4*)(wrow + 4);
      float av[8] = {a0.x, a0.y, a0.z, a0.w, a1v.x, a1v.y, a1v.z, a1v.w};
      float4 xq = *(const float4*)&hs[cil * 64 + tx * 4];
      float xv[4] = {xq.x, xq.y, xq.z, xq.w};
#pragma unroll
      for (int i = 0; i < 8; ++i)
#pragma unroll
        for (int j = 0; j < 4; ++j) acc[i][j] = fmaf(av[i], xv[j], acc[i][j]);
    }
  }
  float* h4b = h4g + (size_t)n * C4 * 256 + l0 + tx * 4;
#pragma unroll
  for (int i = 0; i < 8; ++i) {
    int co = ty * 8 + i;
    float bb = ab1[co];
    float4 o;
    o.x = fmaxf(acc[i][0] + bb, 0.f);
    o.y = fmaxf(acc[i][1] + bb, 0.f);
    o.z = fmaxf(acc[i][2] + bb, 0.f);
    o.w = fmaxf(acc[i][3] + bb, 0.f);
    *(float4*)(h4b + (size_t)co * 256) = o;
  }
}

// ======================================================================
// gemm2: h = sigmoid(a2 @ h4 + ab2) + x2sum. Per (tile,n). LDS 29KB.
__global__ __launch_bounds__(256) void k_gemm2(const float* __restrict__ h4g,
                                               const float* __restrict__ a2,
                                               const float* __restrict__ ab2,
                                               float* __restrict__ hg,
                                               float* __restrict__ x2g) {
  __shared__ float hs[32 * 64];
  __shared__ float wa[32 * WPITCH];
  __shared__ float x2part[16][64];
  int tile = blockIdx.x, n = blockIdx.y;
  int l0 = tile * 64;
  int tid = threadIdx.x, tx = tid & 15, ty = tid >> 4;
  const float* h4b = h4g + (size_t)n * C4 * 256 + l0;

  float acc[8][4];
#pragma unroll
  for (int i = 0; i < 8; ++i)
#pragma unroll
    for (int j = 0; j < 4; ++j) acc[i][j] = 0.f;

  for (int ci0 = 0; ci0 < C4; ci0 += 32) {
    __syncthreads();
    for (int idx = tid; idx < 512; idx += 256) {
      int cil = idx >> 4, q = idx & 15;
      *(float4*)&hs[cil * 64 + 4 * q] =
          *(const float4*)(h4b + (size_t)(ci0 + cil) * 256 + 4 * q);
    }
    for (int idx = tid; idx < 1024; idx += 256) {
      int co = idx >> 3, q = idx & 7;
      float4 v = *(const float4*)(a2 + (size_t)co * C4 + ci0 + 4 * q);
      int r = 4 * q;
      wa[(r + 0) * WPITCH + co] = v.x;
      wa[(r + 1) * WPITCH + co] = v.y;
      wa[(r + 2) * WPITCH + co] = v.z;
      wa[(r + 3) * WPITCH + co] = v.w;
    }
    __syncthreads();
#pragma unroll 8
    for (int cil = 0; cil < 32; ++cil) {
      const float* wrow = wa + cil * WPITCH + ty * 8;
      float4 a0 = *(const float4*)wrow;
      float4 a1v = *(const float4*)(wrow + 4);
      float av[8] = {a0.x, a0.y, a0.z, a0.w, a1v.x, a1v.y, a1v.z, a1v.w};
      float4 xq = *(const float4*)&hs[cil * 64 + tx * 4];
      float xv[4] = {xq.x, xq.y, xq.z, xq.w};
#pragma unroll
      for (int i = 0; i < 8; ++i)
#pragma unroll
        for (int j = 0; j < 4; ++j) acc[i][j] = fmaf(av[i], xv[j], acc[i][j]);
    }
  }
  float s2[4] = {0.f, 0.f, 0.f, 0.f};
  float* hb = hg + (size_t)n * C4 * 256 + l0 + tx * 4;
#pragma unroll
  for (int i = 0; i < 8; ++i) {
    int co = ty * 8 + i;
    float bb = ab2[co];
    float4 o;
    float v0 = acc[i][0] + bb, v1 = acc[i][1] + bb, v2 = acc[i][2] + bb, v3 = acc[i][3] + bb;
    o.x = 1.f / (1.f + expf(-v0));
    o.y = 1.f / (1.f + expf(-v1));
    o.z = 1.f / (1.f + expf(-v2));
    o.w = 1.f / (1.f + expf(-v3));
    s2[0] = fmaf(o.x, o.x, s2[0]);
    s2[1] = fmaf(o.y, o.y, s2[1]);
    s2[2] = fmaf(o.z, o.z, s2[2]);
    s2[3] = fmaf(o.w, o.w, s2[3]);
    *(float4*)(hb + (size_t)co * 256) = o;
  }
#pragma unroll
  for (int j = 0; j < 4; ++j) x2part[ty][tx * 4 + j] = s2[j];
  __syncthreads();
  if (tid < 64) {
    float s = 0.f;
#pragma unroll
    for (int t = 0; t < 16; ++t) s += x2part[t][tid];
    x2g[n * 256 + l0 + tid] = s;
  }
}

// ======================================================================
// dist: per (tile,n): xp = protos(256pad x 128) @ h(128 x 64), distances,
// masked min over l -> pmin. LDS 22KB. Thread tile 8p x 8 consecutive l.
__global__ __launch_bounds__(256) void k_dist(const float* __restrict__ hg,
                                              const float* __restrict__ protos,
                                              const float* __restrict__ p2g,
                                              const float* __restrict__ x2g,
                                              float* __restrict__ pmin, int n0) {
  __shared__ float hc[16 * 64];      // 4KB
  __shared__ float ps[16 * 260];     // 16.6KB (write pattern already ~2-way)
  __shared__ float p2s[PPAD];
  __shared__ float x2s[64];
  int tile = blockIdx.x, n = blockIdx.y;
  int ng = n0 + n, l0 = tile * 64;
  int tid = threadIdx.x, tx = tid & 7, ty = tid >> 3;   // ty in 0..31
  const float* hb = hg + (size_t)n * C4 * 256 + l0;

  p2s[tid] = p2g[tid];
  if (tid < 64) x2s[tid] = x2g[n * 256 + l0 + tid];

  float acc[8][8];
#pragma unroll
  for (int i = 0; i < 8; ++i)
#pragma unroll
    for (int jj = 0; jj < 8; ++jj) acc[i][jj] = 0.f;

  for (int ci0 = 0; ci0 < DD; ci0 += 16) {
    __syncthreads();
    {
      int cil = tid >> 4, q = tid & 15;
      *(float4*)&hc[cil * 64 + 4 * q] =
          *(const float4*)(hb + (size_t)(ci0 + cil) * 256 + 4 * q);
    }
    for (int idx = tid; idx < 1024; idx += 256) {
      int p = idx >> 2, q = idx & 3;
      float4 v = (p < NP) ? *(const float4*)(protos + (size_t)p * DD + ci0 + 4 * q)
                          : make_float4(0.f, 0.f, 0.f, 0.f);
      int r = 4 * q;
      ps[(r + 0) * 260 + p] = v.x;
      ps[(r + 1) * 260 + p] = v.y;
      ps[(r + 2) * 260 + p] = v.z;
      ps[(r + 3) * 260 + p] = v.w;
    }
    __syncthreads();
#pragma unroll 4
    for (int cil = 0; cil < 16; ++cil) {
      const float* prow = ps + cil * 260 + ty * 8;
      float4 a0 = *(const float4*)prow;
      float4 a1v = *(const float4*)(prow + 4);
      float av[8] = {a0.x, a0.y, a0.z, a0.w, a1v.x, a1v.y, a1v.z, a1v.w};
      float4 x0 = *(const float4*)&hc[cil * 64 + tx * 8];
      float4 x1 = *(const float4*)&hc[cil * 64 + tx * 8 + 4];
      float xv[8] = {x0.x, x0.y, x0.z, x0.w, x1.x, x1.y, x1.z, x1.w};
#pragma unroll
      for (int i = 0; i < 8; ++i)
#pragma unroll
        for (int jj = 0; jj < 8; ++jj) acc[i][jj] = fmaf(av[i], xv[jj], acc[i][jj]);
    }
  }
  // epilogue: distances + masked min over the 64 l of this tile
#pragma unroll
  for (int i = 0; i < 8; ++i) {
    int p = ty * 8 + i;
    float p2v = p2s[p];
    float pm = INFINITY;
#pragma unroll
    for (int jj = 0; jj < 8; ++jj) {
      int ll = tx * 8 + jj;
      float dd = x2s[ll] - 2.f * acc[i][jj] + p2v;
      dd = fmaxf(dd, 0.f);
      if (l0 + ll >= L3) dd = INFINITY;
      pm = fminf(pm, dd);
    }
    // reduce over tx (lane bits 0..2)
    pm = fminf(pm, __shfl_xor(pm, 1));
    pm = fminf(pm, __shfl_xor(pm, 2));
    pm = fminf(pm, __shfl_xor(pm, 4));
    if (tx == 0) pmin[((size_t)ng * 4 + tile) * PPAD + p] = pm;
  }
}

// ======================================================================
// reduce 4 tile-mins -> min_d + acts
__global__ __launch_bounds__(256) void k_reduce(const float* __restrict__ pmin,
                                                float* __restrict__ mind_out,
                                                float* __restrict__ acts) {
  int n = blockIdx.x, p = threadIdx.x;
  if (p < NP) {
    const float* pm = pmin + (size_t)n * 4 * PPAD + p;
    float m = pm[0];
    m = fminf(m, pm[PPAD]);
    m = fminf(m, pm[2 * PPAD]);
    m = fminf(m, pm[3 * PPAD]);
    mind_out[(size_t)n * NP + p] = m;
    acts[(size_t)n * NP + p] = logf((m + 1.f) / (m + 1e-4f));
  }
}

// outputs = acts @ last_w.T  (64 x 2, K=4000)
__global__ __launch_bounds__(256) void k_out(const float* __restrict__ acts,
                                             const float* __restrict__ lw,
                                             float* __restrict__ out) {
  __shared__ float r0[256], r1[256];
  int b = blockIdx.x, tid = threadIdx.x;
  float a0 = 0.f, a1 = 0.f;
  for (int j = tid; j < NP * 20; j += 256) {
    float a = acts[(size_t)b * (NP * 20) + j];
    a0 = fmaf(a, lw[j], a0);
    a1 = fmaf(a, lw[NP * 20 + j], a1);
  }
  r0[tid] = a0; r1[tid] = a1;
  __syncthreads();
  for (int s = 128; s > 0; s >>= 1) {
    if (tid < s) { r0[tid] += r0[tid + s]; r1[tid] += r1[tid + s]; }
    __syncthreads();
  }
  if (tid == 0) { out[b * 2] = r0[0]; out[b * 2 + 1] = r1[0]; }
}

// ======================================================================
extern "C" void kernel_launch(void* const* d_in, const int* in_sizes, int n_in,
                              void* d_out, int out_size, void* d_ws, size_t ws_size,
                              hipStream_t stream) {
  const float* x      = (const float*)d_in[0];
  // d_in[1] = metadata (unused)
  const float* w1     = (const float*)d_in[2];
  const float* b1     = (const float*)d_in[3];
  const float* w2     = (const float*)d_in[4];
  const float* b2     = (const float*)d_in[5];
  const float* w3     = (const float*)d_in[6];
  const float* b3     = (const float*)d_in[7];
  const float* a1     = (const float*)d_in[8];
  const float* ab1    = (const float*)d_in[9];
  const float* a2     = (const float*)d_in[10];
  const float* ab2    = (const float*)d_in[11];
  const float* protos = (const float*)d_in[12];
  const float* lw     = (const float*)d_in[13];
  float* out = (float*)d_out;
  float* ws = (float*)d_ws;

  float* h1   = ws + WS_H1;
  float* h2   = ws + WS_H2;
  float* h3   = ws + WS_H1;                        // h3 aliases h1 region
  float* h4   = ws + WS_H2;                        // h4 reuses h2 region (1st half)
  float* hg   = ws + WS_H2 + (size_t)CH * C4 * 256; // h reuses h2 region (2nd half)
  float* pmin = ws + WS_PMIN;
  float* p2   = ws + WS_P2;
  float* acts = ws + WS_ACTS;
  float* x2g  = ws + WS_X2;

  k_p2<<<1, 256, 0, stream>>>(protos, p2);

  for (int c = 0; c < NCHUNK; ++c) {
    int n0 = c * CH;
    k_conv1<<<dim3(2, CH), 256, 0, stream>>>(x, w1, b1, h1, n0);
    k_conv2<<<dim3(8, CH), 256, 0, stream>>>(h1, w2, b2, h2);
    k_conv3<<<dim3(4, 2, CH), 256, 0, stream>>>(h2, w3, b3, h3);
    k_gemm1<<<dim3(4, CH), 256, 0, stream>>>(h3, a1, ab1, h4);
    k_gemm2<<<dim3(4, CH), 256, 0, stream>>>(h4, a2, ab2, hg, x2g);
    k_dist<<<dim3(4, CH), 256, 0, stream>>>(hg, protos, p2, x2g, pmin, n0);
  }

  k_reduce<<<dim3(N_ALL), 256, 0, stream>>>(pmin, out + 128, acts);
  k_out<<<dim3(64), 256, 0, stream>>>(acts, lw, out);
}

// Round 13
// 3141.139 us; speedup vs baseline: 2.4965x; 2.4965x over previous
//
#include <hip/hip_runtime.h>
#include <hip/hip_bf16.h>
#include <math.h>

// ---------------- problem constants ----------------
#define N_ALL 1280     // B*S
#define NCHUNK 8
#define CH (N_ALL / NCHUNK)   // 160 samples per chunk
#define L0 2048
#define L1 1021
#define L2 509
#define L3 254
#define C1 64
#define C2 128
#define C3 256
#define C4 128         // a1/a2 out channels
#define DD 128         // proto dim
#define NP 200         // prototypes
#define PPAD 256
#define H1S 1024       // padded strides
#define H2S 512
#define H3S 256
// NOTE (round 9 lesson): weight-staging pitch MUST be ≡0 mod 4 so the
// float4 LDS reads stay 16B-aligned (pitch 133 -> unaligned ds_read_b128
// -> ~3x kernel slowdown). 132 it is; the staging-write bank conflicts
// this leaves (~6-way) are a small, accepted tax.

// ---------------- workspace layout (floats), macro-derived ----------------
#define H1_FLOATS ((size_t)CH * C1 * H1S)     // 10,485,760 ; h3 aliases (CH*C3*H3S equal)
#define H2_FLOATS ((size_t)CH * C2 * H2S)     // 10,485,760 ; holds h4 (first half) + h (second half)
#define PMIN_FLOATS ((size_t)N_ALL * 4 * PPAD)
#define ACTS_FLOATS ((size_t)N_ALL * NP)
#define WS_H1   ((size_t)0)
#define WS_H2   (WS_H1 + H1_FLOATS)
#define WS_PMIN (WS_H2 + H2_FLOATS)
#define WS_P2   (WS_PMIN + PMIN_FLOATS)
#define WS_ACTS (WS_P2 + PPAD)
#define WS_X2   (WS_ACTS + ACTS_FLOATS)
// total = 22,579,456 floats ~= 90.3 MB

// ======================================================================
// p2[p] = sum_d protos[p][d]^2  (256 entries, 0 for pad)
__global__ __launch_bounds__(256) void k_p2(const float* __restrict__ protos,
                                            float* __restrict__ p2) {
  int p = threadIdx.x;
  if (p < NP) {
    float s = 0.f;
    for (int d = 0; d < DD; ++d) { float v = protos[p * DD + d]; s = fmaf(v, v, s); }
    p2[p] = s;
  } else {
    p2[p] = 0.f;
  }
}

// ======================================================================
// conv1: x(n,2048) -> h1(n_local, 64, 1021 pad 1024), k=7 s=2, relu
__global__ __launch_bounds__(256) void k_conv1(const float* __restrict__ x,
                                               const float* __restrict__ w1,
                                               const float* __restrict__ b1,
                                               float* __restrict__ h1, int n0) {
  __shared__ float xs[L0];
  __shared__ float w1s[C1 * 7];
  __shared__ float b1s[C1];
  int tid = threadIdx.x;
  int chalf = blockIdx.x;
  int n = n0 + blockIdx.y;
  const float* xr = x + (size_t)n * L0;
  for (int i = tid; i < L0 / 4; i += 256)
    ((float4*)xs)[i] = ((const float4*)xr)[i];
  for (int i = tid; i < C1 * 7; i += 256) w1s[i] = w1[i];
  if (tid < C1) b1s[tid] = b1[tid];
  __syncthreads();
  float* hr = h1 + (size_t)blockIdx.y * C1 * H1S;
  for (int cl = 0; cl < 32; ++cl) {
    int c = chalf * 32 + cl;
    float wv0 = w1s[c * 7 + 0], wv1 = w1s[c * 7 + 1], wv2 = w1s[c * 7 + 2],
          wv3 = w1s[c * 7 + 3], wv4 = w1s[c * 7 + 4], wv5 = w1s[c * 7 + 5],
          wv6 = w1s[c * 7 + 6];
    float bb = b1s[c];
    for (int l = tid; l < L1; l += 256) {
      const float* xx = xs + 2 * l;
      float s = bb;
      s = fmaf(wv0, xx[0], s); s = fmaf(wv1, xx[1], s); s = fmaf(wv2, xx[2], s);
      s = fmaf(wv3, xx[3], s); s = fmaf(wv4, xx[4], s); s = fmaf(wv5, xx[5], s);
      s = fmaf(wv6, xx[6], s);
      hr[c * H1S + l] = fmaxf(s, 0.f);
    }
  }
}

// ======================================================================
// conv2: h1(n,64,1024) -> h2(n,128,509 pad 512), k=5 s=2, relu
// 8co x 8l thread tile (l = tx + 16*jj), block tile 128co x 128l.
// LDS: hs[16][260] 16.6KB + wsc[80][132] 42.2KB = 58.9KB -> 2 blocks/CU.
__global__ __launch_bounds__(256) void k_conv2(const float* __restrict__ h1,
                                               const float* __restrict__ w2,
                                               const float* __restrict__ b2,
                                               float* __restrict__ h2) {
  __shared__ float hs[16 * 260];        // input window chunk [cil][260]
  __shared__ float wsc[80 * 132];       // [cil*5+k][co pad 132]
  int tile = blockIdx.x;                // l-tile of 128: 0..3
  int n = blockIdx.y;
  int l0 = tile * 128;
  int c0 = 2 * l0;
  int tid = threadIdx.x;
  int tx = tid & 15, ty = tid >> 4;

  const float* h1b = h1 + (size_t)n * C1 * H1S + c0;

  float acc[8][8];
#pragma unroll
  for (int i = 0; i < 8; ++i)
#pragma unroll
    for (int jj = 0; jj < 8; ++jj) acc[i][jj] = 0.f;

  for (int ci0 = 0; ci0 < C1; ci0 += 16) {
    __syncthreads();
    // stage input chunk rows ci0..ci0+15, cols c0..c0+259 (tail cols feed only
    // padding outputs; reads stay inside the workspace)
    for (int idx = tid; idx < 16 * 65; idx += 256) {
      int cil = idx / 65, m = idx - cil * 65;
      float4 v = *(const float4*)(h1b + (size_t)(ci0 + cil) * H1S + 4 * m);
      *(float4*)&hs[cil * 260 + 4 * m] = v;
    }
    // stage w2 chunk: 128 co x (16 ci x 5 k) -> transposed [r][co]
    for (int idx = tid; idx < C2 * 20; idx += 256) {
      int co = idx / 20, q = idx - co * 20;
      float4 v = *(const float4*)(w2 + (size_t)co * (C1 * 5) + ci0 * 5 + 4 * q);
      int r = 4 * q;
      wsc[(r + 0) * 132 + co] = v.x;
      wsc[(r + 1) * 132 + co] = v.y;
      wsc[(r + 2) * 132 + co] = v.z;
      wsc[(r + 3) * 132 + co] = v.w;
    }
    __syncthreads();
#pragma unroll 2
    for (int cil = 0; cil < 16; ++cil) {
#pragma unroll
      for (int k = 0; k < 5; ++k) {
        const float* wrow = wsc + (cil * 5 + k) * 132 + ty * 8;
        float4 a0 = *(const float4*)wrow;
        float4 a1 = *(const float4*)(wrow + 4);
        float av[8] = {a0.x, a0.y, a0.z, a0.w, a1.x, a1.y, a1.z, a1.w};
        float xv[8];
#pragma unroll
        for (int jj = 0; jj < 8; ++jj) xv[jj] = hs[cil * 260 + 2 * (tx + 16 * jj) + k];
#pragma unroll
        for (int i = 0; i < 8; ++i)
#pragma unroll
          for (int jj = 0; jj < 8; ++jj) acc[i][jj] = fmaf(av[i], xv[jj], acc[i][jj]);
      }
    }
  }
  // epilogue
  float* h2b = h2 + (size_t)n * C2 * H2S + l0;
#pragma unroll
  for (int i = 0; i < 8; ++i) {
    int co = ty * 8 + i;
    float bb = b2[co];
#pragma unroll
    for (int jj = 0; jj < 8; ++jj) {
      int lc = tx + 16 * jj;
      h2b[(size_t)co * H2S + lc] = fmaxf(acc[i][jj] + bb, 0.f);
    }
  }
}

// ======================================================================
// conv3: h2(n,128,512) -> h3(n,256,254 pad 256), k=3 s=2, relu
// 8co x 8l thread tile, block tile 128co x 128l.
// LDS: hs2[16][260] 16.6KB + ws3[48][132] 25.3KB = 41.9KB -> 3 blocks/CU.
__global__ __launch_bounds__(256) void k_conv3(const float* __restrict__ h2,
                                               const float* __restrict__ w3,
                                               const float* __restrict__ b3,
                                               float* __restrict__ h3) {
  __shared__ float hs2[16 * 260];       // chunk window [cil][260]
  __shared__ float ws3[48 * 132];       // [cil*3+k][co pad 132]
  int tile = blockIdx.x;                // l-tile of 128: 0..1
  int co0 = blockIdx.y * 128;
  int n = blockIdx.z;
  int l0 = tile * 128;
  int tid = threadIdx.x;
  int tx = tid & 15, ty = tid >> 4;

  const float* h2b = h2 + (size_t)n * C2 * H2S + 2 * l0;

  float acc[8][8];
#pragma unroll
  for (int i = 0; i < 8; ++i)
#pragma unroll
    for (int jj = 0; jj < 8; ++jj) acc[i][jj] = 0.f;

  for (int ci0 = 0; ci0 < C2; ci0 += 16) {
    __syncthreads();
    for (int idx = tid; idx < 16 * 65; idx += 256) {
      int cil = idx / 65, m = idx - cil * 65;
      float4 v = *(const float4*)(h2b + (size_t)(ci0 + cil) * H2S + 4 * m);
      *(float4*)&hs2[cil * 260 + 4 * m] = v;
    }
    for (int idx = tid; idx < 128 * 12; idx += 256) {
      int co = idx / 12, q = idx - co * 12;
      float4 v = *(const float4*)(w3 + (size_t)(co0 + co) * (C2 * 3) + ci0 * 3 + 4 * q);
      int r = 4 * q;
      ws3[(r + 0) * 132 + co] = v.x;
      ws3[(r + 1) * 132 + co] = v.y;
      ws3[(r + 2) * 132 + co] = v.z;
      ws3[(r + 3) * 132 + co] = v.w;
    }
    __syncthreads();
#pragma unroll 2
    for (int cil = 0; cil < 16; ++cil) {
#pragma unroll
      for (int k = 0; k < 3; ++k) {
        const float* wrow = ws3 + (cil * 3 + k) * 132 + ty * 8;
        float4 a0 = *(const float4*)wrow;
        float4 a1 = *(const float4*)(wrow + 4);
        float av[8] = {a0.x, a0.y, a0.z, a0.w, a1.x, a1.y, a1.z, a1.w};
        float xv[8];
#pragma unroll
        for (int jj = 0; jj < 8; ++jj) xv[jj] = hs2[cil * 260 + 2 * (tx + 16 * jj) + k];
#pragma unroll
        for (int i = 0; i < 8; ++i)
#pragma unroll
          for (int jj = 0; jj < 8; ++jj) acc[i][jj] = fmaf(av[i], xv[jj], acc[i][jj]);
      }
    }
  }
  float* h3b = h3 + (size_t)n * C3 * H3S + l0;
#pragma unroll
  for (int i = 0; i < 8; ++i) {
    int co = co0 + ty * 8 + i;
    float bb = b3[co];
#pragma unroll
    for (int jj = 0; jj < 8; ++jj) {
      int lc = tx + 16 * jj;
      h3b[(size_t)co * H3S + lc] = fmaxf(acc[i][jj] + bb, 0.f);
    }
  }
}

// ======================================================================
// gemm1: h4 = relu(a1 @ h3 + ab1). Per (tile,n): 128co x 64l, K=256.
// LDS 25KB. Thread tile 8co x 4 consecutive l (l = tx*4+j).
__global__ __launch_bounds__(256) void k_gemm1(const float* __restrict__ h3g,
                                               const float* __restrict__ a1,
                                               const float* __restrict__ ab1,
                                               float* __restrict__ h4g) {
  __shared__ float hs[32 * 64];       // 8KB
  __shared__ float wa[32 * 132];      // 16.9KB
  int tile = blockIdx.x, n = blockIdx.y;
  int l0 = tile * 64;
  int tid = threadIdx.x, tx = tid & 15, ty = tid >> 4;
  const float* h3b = h3g + (size_t)n * C3 * H3S + l0;

  float acc[8][4];
#pragma unroll
  for (int i = 0; i < 8; ++i)
#pragma unroll
    for (int j = 0; j < 4; ++j) acc[i][j] = 0.f;

  for (int ci0 = 0; ci0 < C3; ci0 += 32) {
    __syncthreads();
    for (int idx = tid; idx < 512; idx += 256) {
      int cil = idx >> 4, q = idx & 15;
      *(float4*)&hs[cil * 64 + 4 * q] =
          *(const float4*)(h3b + (size_t)(ci0 + cil) * H3S + 4 * q);
    }
    for (int idx = tid; idx < 1024; idx += 256) {
      int co = idx >> 3, q = idx & 7;
      float4 v = *(const float4*)(a1 + (size_t)co * C3 + ci0 + 4 * q);
      int r = 4 * q;
      wa[(r + 0) * 132 + co] = v.x;
      wa[(r + 1) * 132 + co] = v.y;
      wa[(r + 2) * 132 + co] = v.z;
      wa[(r + 3) * 132 + co] = v.w;
    }
    __syncthreads();
#pragma unroll 8
    for (int cil = 0; cil < 32; ++cil) {
      const float* wrow = wa + cil * 132 + ty * 8;
      float4 a0 = *(const float4*)wrow;
      float4 a1v = *(const float4*)(wrow + 4);
      float av[8] = {a0.x, a0.y, a0.z, a0.w, a1v.x, a1v.y, a1v.z, a1v.w};
      float4 xq = *(const float4*)&hs[cil * 64 + tx * 4];
      float xv[4] = {xq.x, xq.y, xq.z, xq.w};
#pragma unroll
      for (int i = 0; i < 8; ++i)
#pragma unroll
        for (int j = 0; j < 4; ++j) acc[i][j] = fmaf(av[i], xv[j], acc[i][j]);
    }
  }
  float* h4b = h4g + (size_t)n * C4 * 256 + l0 + tx * 4;
#pragma unroll
  for (int i = 0; i < 8; ++i) {
    int co = ty * 8 + i;
    float bb = ab1[co];
    float4 o;
    o.x = fmaxf(acc[i][0] + bb, 0.f);
    o.y = fmaxf(acc[i][1] + bb, 0.f);
    o.z = fmaxf(acc[i][2] + bb, 0.f);
    o.w = fmaxf(acc[i][3] + bb, 0.f);
    *(float4*)(h4b + (size_t)co * 256) = o;
  }
}

// ======================================================================
// gemm2: h = sigmoid(a2 @ h4 + ab2) + x2sum. Per (tile,n). LDS 29KB.
__global__ __launch_bounds__(256) void k_gemm2(const float* __restrict__ h4g,
                                               const float* __restrict__ a2,
                                               const float* __restrict__ ab2,
                                               float* __restrict__ hg,
                                               float* __restrict__ x2g) {
  __shared__ float hs[32 * 64];
  __shared__ float wa[32 * 132];
  __shared__ float x2part[16][64];
  int tile = blockIdx.x, n = blockIdx.y;
  int l0 = tile * 64;
  int tid = threadIdx.x, tx = tid & 15, ty = tid >> 4;
  const float* h4b = h4g + (size_t)n * C4 * 256 + l0;

  float acc[8][4];
#pragma unroll
  for (int i = 0; i < 8; ++i)
#pragma unroll
    for (int j = 0; j < 4; ++j) acc[i][j] = 0.f;

  for (int ci0 = 0; ci0 < C4; ci0 += 32) {
    __syncthreads();
    for (int idx = tid; idx < 512; idx += 256) {
      int cil = idx >> 4, q = idx & 15;
      *(float4*)&hs[cil * 64 + 4 * q] =
          *(const float4*)(h4b + (size_t)(ci0 + cil) * 256 + 4 * q);
    }
    for (int idx = tid; idx < 1024; idx += 256) {
      int co = idx >> 3, q = idx & 7;
      float4 v = *(const float4*)(a2 + (size_t)co * C4 + ci0 + 4 * q);
      int r = 4 * q;
      wa[(r + 0) * 132 + co] = v.x;
      wa[(r + 1) * 132 + co] = v.y;
      wa[(r + 2) * 132 + co] = v.z;
      wa[(r + 3) * 132 + co] = v.w;
    }
    __syncthreads();
#pragma unroll 8
    for (int cil = 0; cil < 32; ++cil) {
      const float* wrow = wa + cil * 132 + ty * 8;
      float4 a0 = *(const float4*)wrow;
      float4 a1v = *(const float4*)(wrow + 4);
      float av[8] = {a0.x, a0.y, a0.z, a0.w, a1v.x, a1v.y, a1v.z, a1v.w};
      float4 xq = *(const float4*)&hs[cil * 64 + tx * 4];
      float xv[4] = {xq.x, xq.y, xq.z, xq.w};
#pragma unroll
      for (int i = 0; i < 8; ++i)
#pragma unroll
        for (int j = 0; j < 4; ++j) acc[i][j] = fmaf(av[i], xv[j], acc[i][j]);
    }
  }
  float s2[4] = {0.f, 0.f, 0.f, 0.f};
  float* hb = hg + (size_t)n * C4 * 256 + l0 + tx * 4;
#pragma unroll
  for (int i = 0; i < 8; ++i) {
    int co = ty * 8 + i;
    float bb = ab2[co];
    float4 o;
    float v0 = acc[i][0] + bb, v1 = acc[i][1] + bb, v2 = acc[i][2] + bb, v3 = acc[i][3] + bb;
    o.x = 1.f / (1.f + expf(-v0));
    o.y = 1.f / (1.f + expf(-v1));
    o.z = 1.f / (1.f + expf(-v2));
    o.w = 1.f / (1.f + expf(-v3));
    s2[0] = fmaf(o.x, o.x, s2[0]);
    s2[1] = fmaf(o.y, o.y, s2[1]);
    s2[2] = fmaf(o.z, o.z, s2[2]);
    s2[3] = fmaf(o.w, o.w, s2[3]);
    *(float4*)(hb + (size_t)co * 256) = o;
  }
#pragma unroll
  for (int j = 0; j < 4; ++j) x2part[ty][tx * 4 + j] = s2[j];
  __syncthreads();
  if (tid < 64) {
    float s = 0.f;
#pragma unroll
    for (int t = 0; t < 16; ++t) s += x2part[t][tid];
    x2g[n * 256 + l0 + tid] = s;
  }
}

// ======================================================================
// dist: per (tile,n): xp = protos(256pad x 128) @ h(128 x 64), distances,
// masked min over l -> pmin. LDS 22KB. Thread tile 8p x 8 consecutive l.
__global__ __launch_bounds__(256) void k_dist(const float* __restrict__ hg,
                                              const float* __restrict__ protos,
                                              const float* __restrict__ p2g,
                                              const float* __restrict__ x2g,
                                              float* __restrict__ pmin, int n0) {
  __shared__ float hc[16 * 64];      // 4KB
  __shared__ float ps[16 * 260];     // 16.6KB (aligned pitch; writes ~2-way = free)
  __shared__ float p2s[PPAD];
  __shared__ float x2s[64];
  int tile = blockIdx.x, n = blockIdx.y;
  int ng = n0 + n, l0 = tile * 64;
  int tid = threadIdx.x, tx = tid & 7, ty = tid >> 3;   // ty in 0..31
  const float* hb = hg + (size_t)n * C4 * 256 + l0;

  p2s[tid] = p2g[tid];
  if (tid < 64) x2s[tid] = x2g[n * 256 + l0 + tid];

  float acc[8][8];
#pragma unroll
  for (int i = 0; i < 8; ++i)
#pragma unroll
    for (int jj = 0; jj < 8; ++jj) acc[i][jj] = 0.f;

  for (int ci0 = 0; ci0 < DD; ci0 += 16) {
    __syncthreads();
    {
      int cil = tid >> 4, q = tid & 15;
      *(float4*)&hc[cil * 64 + 4 * q] =
          *(const float4*)(hb + (size_t)(ci0 + cil) * 256 + 4 * q);
    }
    for (int idx = tid; idx < 1024; idx += 256) {
      int p = idx >> 2, q = idx & 3;
      float4 v = (p < NP) ? *(const float4*)(protos + (size_t)p * DD + ci0 + 4 * q)
                          : make_float4(0.f, 0.f, 0.f, 0.f);
      int r = 4 * q;
      ps[(r + 0) * 260 + p] = v.x;
      ps[(r + 1) * 260 + p] = v.y;
      ps[(r + 2) * 260 + p] = v.z;
      ps[(r + 3) * 260 + p] = v.w;
    }
    __syncthreads();
#pragma unroll 4
    for (int cil = 0; cil < 16; ++cil) {
      const float* prow = ps + cil * 260 + ty * 8;
      float4 a0 = *(const float4*)prow;
      float4 a1v = *(const float4*)(prow + 4);
      float av[8] = {a0.x, a0.y, a0.z, a0.w, a1v.x, a1v.y, a1v.z, a1v.w};
      float4 x0 = *(const float4*)&hc[cil * 64 + tx * 8];
      float4 x1 = *(const float4*)&hc[cil * 64 + tx * 8 + 4];
      float xv[8] = {x0.x, x0.y, x0.z, x0.w, x1.x, x1.y, x1.z, x1.w};
#pragma unroll
      for (int i = 0; i < 8; ++i)
#pragma unroll
        for (int jj = 0; jj < 8; ++jj) acc[i][jj] = fmaf(av[i], xv[jj], acc[i][jj]);
    }
  }
  // epilogue: distances + masked min over the 64 l of this tile
#pragma unroll
  for (int i = 0; i < 8; ++i) {
    int p = ty * 8 + i;
    float p2v = p2s[p];
    float pm = INFINITY;
#pragma unroll
    for (int jj = 0; jj < 8; ++jj) {
      int ll = tx * 8 + jj;
      float dd = x2s[ll] - 2.f * acc[i][jj] + p2v;
      dd = fmaxf(dd, 0.f);
      if (l0 + ll >= L3) dd = INFINITY;
      pm = fminf(pm, dd);
    }
    // reduce over tx (lane bits 0..2)
    pm = fminf(pm, __shfl_xor(pm, 1));
    pm = fminf(pm, __shfl_xor(pm, 2));
    pm = fminf(pm, __shfl_xor(pm, 4));
    if (tx == 0) pmin[((size_t)ng * 4 + tile) * PPAD + p] = pm;
  }
}

// ======================================================================
// reduce 4 tile-mins -> min_d + acts
__global__ __launch_bounds__(256) void k_reduce(const float* __restrict__ pmin,
                                                float* __restrict__ mind_out,
                                                float* __restrict__ acts) {
  int n = blockIdx.x, p = threadIdx.x;
  if (p < NP) {
    const float* pm = pmin + (size_t)n * 4 * PPAD + p;
    float m = pm[0];
    m = fminf(m, pm[PPAD]);
    m = fminf(m, pm[2 * PPAD]);
    m = fminf(m, pm[3 * PPAD]);
    mind_out[(size_t)n * NP + p] = m;
    acts[(size_t)n * NP + p] = logf((m + 1.f) / (m + 1e-4f));
  }
}

// outputs = acts @ last_w.T  (64 x 2, K=4000)
__global__ __launch_bounds__(256) void k_out(const float* __restrict__ acts,
                                             const float* __restrict__ lw,
                                             float* __restrict__ out) {
  __shared__ float r0[256], r1[256];
  int b = blockIdx.x, tid = threadIdx.x;
  float a0 = 0.f, a1 = 0.f;
  for (int j = tid; j < NP * 20; j += 256) {
    float a = acts[(size_t)b * (NP * 20) + j];
    a0 = fmaf(a, lw[j], a0);
    a1 = fmaf(a, lw[NP * 20 + j], a1);
  }
  r0[tid] = a0; r1[tid] = a1;
  __syncthreads();
  for (int s = 128; s > 0; s >>= 1) {
    if (tid < s) { r0[tid] += r0[tid + s]; r1[tid] += r1[tid + s]; }
    __syncthreads();
  }
  if (tid == 0) { out[b * 2] = r0[0]; out[b * 2 + 1] = r1[0]; }
}

// ======================================================================
extern "C" void kernel_launch(void* const* d_in, const int* in_sizes, int n_in,
                              void* d_out, int out_size, void* d_ws, size_t ws_size,
                              hipStream_t stream) {
  const float* x      = (const float*)d_in[0];
  // d_in[1] = metadata (unused)
  const float* w1     = (const float*)d_in[2];
  const float* b1     = (const float*)d_in[3];
  const float* w2     = (const float*)d_in[4];
  const float* b2     = (const float*)d_in[5];
  const float* w3     = (const float*)d_in[6];
  const float* b3     = (const float*)d_in[7];
  const float* a1     = (const float*)d_in[8];
  const float* ab1    = (const float*)d_in[9];
  const float* a2     = (const float*)d_in[10];
  const float* ab2    = (const float*)d_in[11];
  const float* protos = (const float*)d_in[12];
  const float* lw     = (const float*)d_in[13];
  float* out = (float*)d_out;
  float* ws = (float*)d_ws;

  float* h1   = ws + WS_H1;
  float* h2   = ws + WS_H2;
  float* h3   = ws + WS_H1;                        // h3 aliases h1 region
  float* h4   = ws + WS_H2;                        // h4 reuses h2 region (1st half)
  float* hg   = ws + WS_H2 + (size_t)CH * C4 * 256; // h reuses h2 region (2nd half)
  float* pmin = ws + WS_PMIN;
  float* p2   = ws + WS_P2;
  float* acts = ws + WS_ACTS;
  float* x2g  = ws + WS_X2;

  k_p2<<<1, 256, 0, stream>>>(protos, p2);

  for (int c = 0; c < NCHUNK; ++c) {
    int n0 = c * CH;
    k_conv1<<<dim3(2, CH), 256, 0, stream>>>(x, w1, b1, h1, n0);
    k_conv2<<<dim3(4, CH), 256, 0, stream>>>(h1, w2, b2, h2);
    k_conv3<<<dim3(2, 2, CH), 256, 0, stream>>>(h2, w3, b3, h3);
    k_gemm1<<<dim3(4, CH), 256, 0, stream>>>(h3, a1, ab1, h4);
    k_gemm2<<<dim3(4, CH), 256, 0, stream>>>(h4, a2, ab2, hg, x2g);
    k_dist<<<dim3(4, CH), 256, 0, stream>>>(hg, protos, p2, x2g, pmin, n0);
  }

  k_reduce<<<dim3(N_ALL), 256, 0, stream>>>(pmin, out + 128, acts);
  k_out<<<dim3(64), 256, 0, stream>>>(acts, lw, out);
}

// Round 14
// 2527.576 us; speedup vs baseline: 3.1025x; 1.2427x over previous
//
#include <hip/hip_runtime.h>
#include <hip/hip_bf16.h>
#include <math.h>

// ---------------- problem constants ----------------
#define N_ALL 1280     // B*S
#define L0 2048
#define L1 1021
#define L2 509
#define L3 254
#define C1 64
#define C2 128
#define C3 256
#define C4 128         // a1/a2 out channels
#define DD 128         // proto dim
#define NP 200         // prototypes
#define PPAD 256
#define H1S 1024       // padded strides
#define H2S 512
#define H3S 256
// Lessons encoded here:
//  - r9: LDS pitch must be ≡0 mod 4 (float4 reads need 16B alignment); 132 it is.
//  - r13: these kernels are LATENCY-bound — occupancy (blocks/CU × grid size) is
//    the lever, not FMA:LDS ratio. Keep LDS small, grids big.
// Per-sample tensor sizes all equal 65536 floats (C1*H1S = C2*H2S = C3*H3S =
// 2*C4*256), so workspace offsets scale linearly with the runtime chunk size.

// ======================================================================
// p2[p] = sum_d protos[p][d]^2  (256 entries, 0 for pad)
__global__ __launch_bounds__(256) void k_p2(const float* __restrict__ protos,
                                            float* __restrict__ p2) {
  int p = threadIdx.x;
  if (p < NP) {
    float s = 0.f;
    for (int d = 0; d < DD; ++d) { float v = protos[p * DD + d]; s = fmaf(v, v, s); }
    p2[p] = s;
  } else {
    p2[p] = 0.f;
  }
}

// ======================================================================
// conv1: x(n,2048) -> h1(n_local, 64, 1021 pad 1024), k=7 s=2, relu
__global__ __launch_bounds__(256) void k_conv1(const float* __restrict__ x,
                                               const float* __restrict__ w1,
                                               const float* __restrict__ b1,
                                               float* __restrict__ h1, int n0) {
  __shared__ float xs[L0];
  __shared__ float w1s[C1 * 7];
  __shared__ float b1s[C1];
  int tid = threadIdx.x;
  int chalf = blockIdx.x;
  int n = n0 + blockIdx.y;
  const float* xr = x + (size_t)n * L0;
  for (int i = tid; i < L0 / 4; i += 256)
    ((float4*)xs)[i] = ((const float4*)xr)[i];
  for (int i = tid; i < C1 * 7; i += 256) w1s[i] = w1[i];
  if (tid < C1) b1s[tid] = b1[tid];
  __syncthreads();
  float* hr = h1 + (size_t)blockIdx.y * C1 * H1S;
  for (int cl = 0; cl < 32; ++cl) {
    int c = chalf * 32 + cl;
    float wv0 = w1s[c * 7 + 0], wv1 = w1s[c * 7 + 1], wv2 = w1s[c * 7 + 2],
          wv3 = w1s[c * 7 + 3], wv4 = w1s[c * 7 + 4], wv5 = w1s[c * 7 + 5],
          wv6 = w1s[c * 7 + 6];
    float bb = b1s[c];
    for (int l = tid; l < L1; l += 256) {
      const float* xx = xs + 2 * l;
      float s = bb;
      s = fmaf(wv0, xx[0], s); s = fmaf(wv1, xx[1], s); s = fmaf(wv2, xx[2], s);
      s = fmaf(wv3, xx[3], s); s = fmaf(wv4, xx[4], s); s = fmaf(wv5, xx[5], s);
      s = fmaf(wv6, xx[6], s);
      hr[c * H1S + l] = fmaxf(s, 0.f);
    }
  }
}

// ======================================================================
// conv2: h1(n,64,1024) -> h2(n,128,509 pad 512), k=5 s=2, relu
// Round-8 geometry (64-l tile, 8co x 4l/thread) with 8-ci K-chunks:
// LDS hs[8][136] 4.4KB + wsc[40][132] 21.1KB = 25.5KB -> LDS cap 6 blocks/CU
// (VGPR ~68 caps at 4) vs round-8's 3. Occupancy is the lever (r13).
__global__ __launch_bounds__(256) void k_conv2(const float* __restrict__ h1,
                                               const float* __restrict__ w2,
                                               const float* __restrict__ b2,
                                               float* __restrict__ h2) {
  __shared__ float hs[8 * 136];         // input window chunk [cil][136]
  __shared__ float wsc[40 * 132];       // [cil*5+k][co pad 132]
  int tile = blockIdx.x;                // l-tile of 64: 0..7
  int n = blockIdx.y;
  int l0 = tile * 64;
  int c0 = 2 * l0;
  int tid = threadIdx.x;
  int tx = tid & 15, ty = tid >> 4;

  const float* h1b = h1 + (size_t)n * C1 * H1S + c0;

  float acc[8][4];
#pragma unroll
  for (int i = 0; i < 8; ++i)
#pragma unroll
    for (int j = 0; j < 4; ++j) acc[i][j] = 0.f;

  for (int ci0 = 0; ci0 < C1; ci0 += 8) {
    __syncthreads();
    // stage input chunk rows ci0..ci0+7, cols c0..c0+131
    for (int idx = tid; idx < 8 * 33; idx += 256) {
      int cil = idx / 33, m4 = idx - cil * 33;
      float4 v = *(const float4*)(h1b + (size_t)(ci0 + cil) * H1S + 4 * m4);
      *(float4*)&hs[cil * 136 + 4 * m4] = v;
    }
    // stage w2 chunk: 128 co x (8 ci x 5 k) -> transposed [r][co]
    for (int idx = tid; idx < C2 * 10; idx += 256) {
      int co = idx / 10, q = idx - co * 10;
      float4 v = *(const float4*)(w2 + (size_t)co * (C1 * 5) + ci0 * 5 + 4 * q);
      int r = 4 * q;
      wsc[(r + 0) * 132 + co] = v.x;
      wsc[(r + 1) * 132 + co] = v.y;
      wsc[(r + 2) * 132 + co] = v.z;
      wsc[(r + 3) * 132 + co] = v.w;
    }
    __syncthreads();
#pragma unroll 2
    for (int cil = 0; cil < 8; ++cil) {
#pragma unroll
      for (int k = 0; k < 5; ++k) {
        const float* wrow = wsc + (cil * 5 + k) * 132 + ty * 8;
        float4 a0 = *(const float4*)wrow;
        float4 a1 = *(const float4*)(wrow + 4);
        float av[8] = {a0.x, a0.y, a0.z, a0.w, a1.x, a1.y, a1.z, a1.w};
        float xv[4];
#pragma unroll
        for (int j = 0; j < 4; ++j) xv[j] = hs[cil * 136 + 2 * (tx + 16 * j) + k];
#pragma unroll
        for (int i = 0; i < 8; ++i)
#pragma unroll
          for (int j = 0; j < 4; ++j) acc[i][j] = fmaf(av[i], xv[j], acc[i][j]);
      }
    }
  }
  // epilogue
  float bb[8];
#pragma unroll
  for (int i = 0; i < 8; ++i) bb[i] = b2[ty * 8 + i];
  float* h2b = h2 + (size_t)n * C2 * H2S + l0;
#pragma unroll
  for (int i = 0; i < 8; ++i) {
    int co = ty * 8 + i;
#pragma unroll
    for (int j = 0; j < 4; ++j) {
      int lc = tx + 16 * j;
      h2b[(size_t)co * H2S + lc] = fmaxf(acc[i][j] + bb[i], 0.f);
    }
  }
}

// ======================================================================
// conv3: h2(n,128,512) -> h3(n,256,254 pad 256), k=3 s=2, relu
// Round-8 geometry exactly (measured best: 140us/chunk-dispatch).
__global__ __launch_bounds__(256) void k_conv3(const float* __restrict__ h2,
                                               const float* __restrict__ w3,
                                               const float* __restrict__ b3,
                                               float* __restrict__ h3) {
  __shared__ float hs2[16 * 136];       // chunk window [cil][136]
  __shared__ float ws3[48 * 132];       // [cil*3+k][co pad 132]
  int tile = blockIdx.x;                // l-tile of 64: 0..3
  int co0 = blockIdx.y * 128;
  int n = blockIdx.z;
  int l0 = tile * 64;
  int tid = threadIdx.x;
  int tx = tid & 15, ty = tid >> 4;

  const float* h2b = h2 + (size_t)n * C2 * H2S + 2 * l0;

  float acc[8][4];
#pragma unroll
  for (int i = 0; i < 8; ++i)
#pragma unroll
    for (int j = 0; j < 4; ++j) acc[i][j] = 0.f;

  for (int ci0 = 0; ci0 < C2; ci0 += 16) {
    __syncthreads();
    for (int idx = tid; idx < 16 * 33; idx += 256) {
      int cil = idx / 33, m4 = idx - cil * 33;
      float4 v = *(const float4*)(h2b + (size_t)(ci0 + cil) * H2S + 4 * m4);
      *(float4*)&hs2[cil * 136 + 4 * m4] = v;
    }
    for (int idx = tid; idx < 128 * 12; idx += 256) {
      int co = idx / 12, q = idx - co * 12;
      float4 v = *(const float4*)(w3 + (size_t)(co0 + co) * (C2 * 3) + ci0 * 3 + 4 * q);
      int r = 4 * q;
      ws3[(r + 0) * 132 + co] = v.x;
      ws3[(r + 1) * 132 + co] = v.y;
      ws3[(r + 2) * 132 + co] = v.z;
      ws3[(r + 3) * 132 + co] = v.w;
    }
    __syncthreads();
#pragma unroll 2
    for (int cil = 0; cil < 16; ++cil) {
#pragma unroll
      for (int k = 0; k < 3; ++k) {
        const float* wrow = ws3 + (cil * 3 + k) * 132 + ty * 8;
        float4 a0 = *(const float4*)wrow;
        float4 a1 = *(const float4*)(wrow + 4);
        float av[8] = {a0.x, a0.y, a0.z, a0.w, a1.x, a1.y, a1.z, a1.w};
        float xv[4];
#pragma unroll
        for (int j = 0; j < 4; ++j) xv[j] = hs2[cil * 136 + 2 * (tx + 16 * j) + k];
#pragma unroll
        for (int i = 0; i < 8; ++i)
#pragma unroll
          for (int j = 0; j < 4; ++j) acc[i][j] = fmaf(av[i], xv[j], acc[i][j]);
      }
    }
  }
  float bb[8];
#pragma unroll
  for (int i = 0; i < 8; ++i) bb[i] = b3[co0 + ty * 8 + i];
  float* h3b = h3 + (size_t)n * C3 * H3S + l0;
#pragma unroll
  for (int i = 0; i < 8; ++i) {
    int co = co0 + ty * 8 + i;
#pragma unroll
    for (int j = 0; j < 4; ++j) {
      int lc = tx + 16 * j;
      h3b[(size_t)co * H3S + lc] = fmaxf(acc[i][j] + bb[i], 0.f);
    }
  }
}

// ======================================================================
// gemm1: h4 = relu(a1 @ h3 + ab1). Per (tile,n): 128co x 64l, K=256.
__global__ __launch_bounds__(256) void k_gemm1(const float* __restrict__ h3g,
                                               const float* __restrict__ a1,
                                               const float* __restrict__ ab1,
                                               float* __restrict__ h4g) {
  __shared__ float hs[32 * 64];       // 8KB
  __shared__ float wa[32 * 132];      // 16.9KB
  int tile = blockIdx.x, n = blockIdx.y;
  int l0 = tile * 64;
  int tid = threadIdx.x, tx = tid & 15, ty = tid >> 4;
  const float* h3b = h3g + (size_t)n * C3 * H3S + l0;

  float acc[8][4];
#pragma unroll
  for (int i = 0; i < 8; ++i)
#pragma unroll
    for (int j = 0; j < 4; ++j) acc[i][j] = 0.f;

  for (int ci0 = 0; ci0 < C3; ci0 += 32) {
    __syncthreads();
    for (int idx = tid; idx < 512; idx += 256) {
      int cil = idx >> 4, q = idx & 15;
      *(float4*)&hs[cil * 64 + 4 * q] =
          *(const float4*)(h3b + (size_t)(ci0 + cil) * H3S + 4 * q);
    }
    for (int idx = tid; idx < 1024; idx += 256) {
      int co = idx >> 3, q = idx & 7;
      float4 v = *(const float4*)(a1 + (size_t)co * C3 + ci0 + 4 * q);
      int r = 4 * q;
      wa[(r + 0) * 132 + co] = v.x;
      wa[(r + 1) * 132 + co] = v.y;
      wa[(r + 2) * 132 + co] = v.z;
      wa[(r + 3) * 132 + co] = v.w;
    }
    __syncthreads();
#pragma unroll 8
    for (int cil = 0; cil < 32; ++cil) {
      const float* wrow = wa + cil * 132 + ty * 8;
      float4 a0 = *(const float4*)wrow;
      float4 a1v = *(const float4*)(wrow + 4);
      float av[8] = {a0.x, a0.y, a0.z, a0.w, a1v.x, a1v.y, a1v.z, a1v.w};
      float4 xq = *(const float4*)&hs[cil * 64 + tx * 4];
      float xv[4] = {xq.x, xq.y, xq.z, xq.w};
#pragma unroll
      for (int i = 0; i < 8; ++i)
#pragma unroll
        for (int j = 0; j < 4; ++j) acc[i][j] = fmaf(av[i], xv[j], acc[i][j]);
    }
  }
  float* h4b = h4g + (size_t)n * C4 * 256 + l0 + tx * 4;
#pragma unroll
  for (int i = 0; i < 8; ++i) {
    int co = ty * 8 + i;
    float bb = ab1[co];
    float4 o;
    o.x = fmaxf(acc[i][0] + bb, 0.f);
    o.y = fmaxf(acc[i][1] + bb, 0.f);
    o.z = fmaxf(acc[i][2] + bb, 0.f);
    o.w = fmaxf(acc[i][3] + bb, 0.f);
    *(float4*)(h4b + (size_t)co * 256) = o;
  }
}

// ======================================================================
// gemm2: h = sigmoid(a2 @ h4 + ab2) + x2sum. Per (tile,n). LDS 29KB.
__global__ __launch_bounds__(256) void k_gemm2(const float* __restrict__ h4g,
                                               const float* __restrict__ a2,
                                               const float* __restrict__ ab2,
                                               float* __restrict__ hg,
                                               float* __restrict__ x2g) {
  __shared__ float hs[32 * 64];
  __shared__ float wa[32 * 132];
  __shared__ float x2part[16][64];
  int tile = blockIdx.x, n = blockIdx.y;
  int l0 = tile * 64;
  int tid = threadIdx.x, tx = tid & 15, ty = tid >> 4;
  const float* h4b = h4g + (size_t)n * C4 * 256 + l0;

  float acc[8][4];
#pragma unroll
  for (int i = 0; i < 8; ++i)
#pragma unroll
    for (int j = 0; j < 4; ++j) acc[i][j] = 0.f;

  for (int ci0 = 0; ci0 < C4; ci0 += 32) {
    __syncthreads();
    for (int idx = tid; idx < 512; idx += 256) {
      int cil = idx >> 4, q = idx & 15;
      *(float4*)&hs[cil * 64 + 4 * q] =
          *(const float4*)(h4b + (size_t)(ci0 + cil) * 256 + 4 * q);
    }
    for (int idx = tid; idx < 1024; idx += 256) {
      int co = idx >> 3, q = idx & 7;
      float4 v = *(const float4*)(a2 + (size_t)co * C4 + ci0 + 4 * q);
      int r = 4 * q;
      wa[(r + 0) * 132 + co] = v.x;
      wa[(r + 1) * 132 + co] = v.y;
      wa[(r + 2) * 132 + co] = v.z;
      wa[(r + 3) * 132 + co] = v.w;
    }
    __syncthreads();
#pragma unroll 8
    for (int cil = 0; cil < 32; ++cil) {
      const float* wrow = wa + cil * 132 + ty * 8;
      float4 a0 = *(const float4*)wrow;
      float4 a1v = *(const float4*)(wrow + 4);
      float av[8] = {a0.x, a0.y, a0.z, a0.w, a1v.x, a1v.y, a1v.z, a1v.w};
      float4 xq = *(const float4*)&hs[cil * 64 + tx * 4];
      float xv[4] = {xq.x, xq.y, xq.z, xq.w};
#pragma unroll
      for (int i = 0; i < 8; ++i)
#pragma unroll
        for (int j = 0; j < 4; ++j) acc[i][j] = fmaf(av[i], xv[j], acc[i][j]);
    }
  }
  float s2[4] = {0.f, 0.f, 0.f, 0.f};
  float* hb = hg + (size_t)n * C4 * 256 + l0 + tx * 4;
#pragma unroll
  for (int i = 0; i < 8; ++i) {
    int co = ty * 8 + i;
    float bb = ab2[co];
    float4 o;
    float v0 = acc[i][0] + bb, v1 = acc[i][1] + bb, v2 = acc[i][2] + bb, v3 = acc[i][3] + bb;
    o.x = 1.f / (1.f + expf(-v0));
    o.y = 1.f / (1.f + expf(-v1));
    o.z = 1.f / (1.f + expf(-v2));
    o.w = 1.f / (1.f + expf(-v3));
    s2[0] = fmaf(o.x, o.x, s2[0]);
    s2[1] = fmaf(o.y, o.y, s2[1]);
    s2[2] = fmaf(o.z, o.z, s2[2]);
    s2[3] = fmaf(o.w, o.w, s2[3]);
    *(float4*)(hb + (size_t)co * 256) = o;
  }
#pragma unroll
  for (int j = 0; j < 4; ++j) x2part[ty][tx * 4 + j] = s2[j];
  __syncthreads();
  if (tid < 64) {
    float s = 0.f;
#pragma unroll
    for (int t = 0; t < 16; ++t) s += x2part[t][tid];
    x2g[n * 256 + l0 + tid] = s;
  }
}

// ======================================================================
// dist: per (tile,n): xp = protos(256pad x 128) @ h(128 x 64), distances,
// masked min over l -> pmin. LDS 22KB. Thread tile 8p x 8 consecutive l.
__global__ __launch_bounds__(256) void k_dist(const float* __restrict__ hg,
                                              const float* __restrict__ protos,
                                              const float* __restrict__ p2g,
                                              const float* __restrict__ x2g,
                                              float* __restrict__ pmin, int n0) {
  __shared__ float hc[16 * 64];      // 4KB
  __shared__ float ps[16 * 260];     // 16.6KB (aligned pitch; writes ~2-way = free)
  __shared__ float p2s[PPAD];
  __shared__ float x2s[64];
  int tile = blockIdx.x, n = blockIdx.y;
  int ng = n0 + n, l0 = tile * 64;
  int tid = threadIdx.x, tx = tid & 7, ty = tid >> 3;   // ty in 0..31
  const float* hb = hg + (size_t)n * C4 * 256 + l0;

  p2s[tid] = p2g[tid];
  if (tid < 64) x2s[tid] = x2g[n * 256 + l0 + tid];

  float acc[8][8];
#pragma unroll
  for (int i = 0; i < 8; ++i)
#pragma unroll
    for (int jj = 0; jj < 8; ++jj) acc[i][jj] = 0.f;

  for (int ci0 = 0; ci0 < DD; ci0 += 16) {
    __syncthreads();
    {
      int cil = tid >> 4, q = tid & 15;
      *(float4*)&hc[cil * 64 + 4 * q] =
          *(const float4*)(hb + (size_t)(ci0 + cil) * 256 + 4 * q);
    }
    for (int idx = tid; idx < 1024; idx += 256) {
      int p = idx >> 2, q = idx & 3;
      float4 v = (p < NP) ? *(const float4*)(protos + (size_t)p * DD + ci0 + 4 * q)
                          : make_float4(0.f, 0.f, 0.f, 0.f);
      int r = 4 * q;
      ps[(r + 0) * 260 + p] = v.x;
      ps[(r + 1) * 260 + p] = v.y;
      ps[(r + 2) * 260 + p] = v.z;
      ps[(r + 3) * 260 + p] = v.w;
    }
    __syncthreads();
#pragma unroll 4
    for (int cil = 0; cil < 16; ++cil) {
      const float* prow = ps + cil * 260 + ty * 8;
      float4 a0 = *(const float4*)prow;
      float4 a1v = *(const float4*)(prow + 4);
      float av[8] = {a0.x, a0.y, a0.z, a0.w, a1v.x, a1v.y, a1v.z, a1v.w};
      float4 x0 = *(const float4*)&hc[cil * 64 + tx * 8];
      float4 x1 = *(const float4*)&hc[cil * 64 + tx * 8 + 4];
      float xv[8] = {x0.x, x0.y, x0.z, x0.w, x1.x, x1.y, x1.z, x1.w};
#pragma unroll
      for (int i = 0; i < 8; ++i)
#pragma unroll
        for (int jj = 0; jj < 8; ++jj) acc[i][jj] = fmaf(av[i], xv[jj], acc[i][jj]);
    }
  }
  // epilogue: distances + masked min over the 64 l of this tile
#pragma unroll
  for (int i = 0; i < 8; ++i) {
    int p = ty * 8 + i;
    float p2v = p2s[p];
    float pm = INFINITY;
#pragma unroll
    for (int jj = 0; jj < 8; ++jj) {
      int ll = tx * 8 + jj;
      float dd = x2s[ll] - 2.f * acc[i][jj] + p2v;
      dd = fmaxf(dd, 0.f);
      if (l0 + ll >= L3) dd = INFINITY;
      pm = fminf(pm, dd);
    }
    // reduce over tx (lane bits 0..2)
    pm = fminf(pm, __shfl_xor(pm, 1));
    pm = fminf(pm, __shfl_xor(pm, 2));
    pm = fminf(pm, __shfl_xor(pm, 4));
    if (tx == 0) pmin[((size_t)ng * 4 + tile) * PPAD + p] = pm;
  }
}

// ======================================================================
// reduce 4 tile-mins -> min_d + acts
__global__ __launch_bounds__(256) void k_reduce(const float* __restrict__ pmin,
                                                float* __restrict__ mind_out,
                                                float* __restrict__ acts) {
  int n = blockIdx.x, p = threadIdx.x;
  if (p < NP) {
    const float* pm = pmin + (size_t)n * 4 * PPAD + p;
    float m = pm[0];
    m = fminf(m, pm[PPAD]);
    m = fminf(m, pm[2 * PPAD]);
    m = fminf(m, pm[3 * PPAD]);
    mind_out[(size_t)n * NP + p] = m;
    acts[(size_t)n * NP + p] = logf((m + 1.f) / (m + 1e-4f));
  }
}

// outputs = acts @ last_w.T  (64 x 2, K=4000)
__global__ __launch_bounds__(256) void k_out(const float* __restrict__ acts,
                                             const float* __restrict__ lw,
                                             float* __restrict__ out) {
  __shared__ float r0[256], r1[256];
  int b = blockIdx.x, tid = threadIdx.x;
  float a0 = 0.f, a1 = 0.f;
  for (int j = tid; j < NP * 20; j += 256) {
    float a = acts[(size_t)b * (NP * 20) + j];
    a0 = fmaf(a, lw[j], a0);
    a1 = fmaf(a, lw[NP * 20 + j], a1);
  }
  r0[tid] = a0; r1[tid] = a1;
  __syncthreads();
  for (int s = 128; s > 0; s >>= 1) {
    if (tid < s) { r0[tid] += r0[tid + s]; r1[tid] += r1[tid + s]; }
    __syncthreads();
  }
  if (tid == 0) { out[b * 2] = r0[0]; out[b * 2 + 1] = r1[0]; }
}

// ======================================================================
extern "C" void kernel_launch(void* const* d_in, const int* in_sizes, int n_in,
                              void* d_out, int out_size, void* d_ws, size_t ws_size,
                              hipStream_t stream) {
  const float* x      = (const float*)d_in[0];
  // d_in[1] = metadata (unused)
  const float* w1     = (const float*)d_in[2];
  const float* b1     = (const float*)d_in[3];
  const float* w2     = (const float*)d_in[4];
  const float* b2     = (const float*)d_in[5];
  const float* w3     = (const float*)d_in[6];
  const float* b3     = (const float*)d_in[7];
  const float* a1     = (const float*)d_in[8];
  const float* ab1    = (const float*)d_in[9];
  const float* a2     = (const float*)d_in[10];
  const float* ab2    = (const float*)d_in[11];
  const float* protos = (const float*)d_in[12];
  const float* lw     = (const float*)d_in[13];
  float* out = (float*)d_out;
  float* ws = (float*)d_ws;

  // Runtime chunk sizing: pick largest ch (samples per chunk) that fits ws.
  // Deterministic per session (ws_size fixed) -> graph-capture safe.
  size_t ws_floats = ws_size / sizeof(float);
  int ch = 160;  // proven fallback (round 3+: 90.3 MB)
  {
    const int cands[4] = {1280, 640, 320, 160};
    for (int i = 0; i < 4; ++i) {
      int c = cands[i];
      size_t need = 2ull * (size_t)c * 65536ull          // h1(=h3) + h2(=h4+hg)
                    + (size_t)N_ALL * 4 * PPAD           // pmin
                    + PPAD                               // p2
                    + (size_t)N_ALL * NP                 // acts
                    + (size_t)c * 256;                   // x2g
      if (ws_floats >= need) { ch = c; break; }
    }
  }
  size_t chf = (size_t)ch * 65536;
  float* h1   = ws;                                  // h3 aliases h1 region
  float* h3   = ws;
  float* h2   = ws + chf;                            // h4 = first half, hg = second
  float* h4   = ws + chf;
  float* hg   = ws + chf + (size_t)ch * 32768;
  float* pmin = ws + 2 * chf;
  float* p2   = pmin + (size_t)N_ALL * 4 * PPAD;
  float* acts = p2 + PPAD;
  float* x2g  = acts + (size_t)N_ALL * NP;

  k_p2<<<1, 256, 0, stream>>>(protos, p2);

  int nchunk = N_ALL / ch;
  for (int c = 0; c < nchunk; ++c) {
    int n0 = c * ch;
    k_conv1<<<dim3(2, ch), 256, 0, stream>>>(x, w1, b1, h1, n0);
    k_conv2<<<dim3(8, ch), 256, 0, stream>>>(h1, w2, b2, h2);
    k_conv3<<<dim3(4, 2, ch), 256, 0, stream>>>(h2, w3, b3, h3);
    k_gemm1<<<dim3(4, ch), 256, 0, stream>>>(h3, a1, ab1, h4);
    k_gemm2<<<dim3(4, ch), 256, 0, stream>>>(h4, a2, ab2, hg, x2g);
    k_dist<<<dim3(4, ch), 256, 0, stream>>>(hg, protos, p2, x2g, pmin, n0);
  }

  k_reduce<<<dim3(N_ALL), 256, 0, stream>>>(pmin, out + 128, acts);
  k_out<<<dim3(64), 256, 0, stream>>>(acts, lw, out);
}